// Round 2
// baseline (478.390 us; speedup 1.0000x reference)
//
#include <hip/hip_runtime.h>
#include <hip/hip_bf16.h>

#define BB 16
#define NN 2048
#define FIN 256
#define FO 64
#define CH 512  // k2 j-chunk per staging round

typedef __bf16 bf16x8 __attribute__((ext_vector_type(8)));
typedef __bf16 bf16x4 __attribute__((ext_vector_type(4)));
typedef float  f32x4  __attribute__((ext_vector_type(4)));
typedef int    i32x4  __attribute__((ext_vector_type(4)));

// ---------------- K0: tiny prep (1 block) ----------------
__global__ void k0_prep(const float* __restrict__ weight, const float* __restrict__ w2,
                        __bf16* __restrict__ Wt, float* __restrict__ vsrc,
                        float* __restrict__ vdst) {
    int t = threadIdx.x;  // 256 threads
    for (int idx = t; idx < FIN * FO; idx += 256) {
        int k = idx >> 6, o = idx & 63;
        Wt[o * FIN + k] = (__bf16)weight[idx];  // idx = k*64+o
    }
    float a = 0.f, d = 0.f;
    for (int o = 0; o < FO; ++o) {
        float wv = weight[t * FO + o];
        a += wv * w2[o];
        d += wv * w2[FO + o];
    }
    vsrc[t] = a;
    vdst[t] = d;
}

// ---------------- K1: h GEMM (MFMA bf16) + exact fp32 s_src/s_dst ------------
__global__ __launch_bounds__(256) void k1_gemm(
    const float* __restrict__ x, const __bf16* __restrict__ Wt,
    const float* __restrict__ vsrc, const float* __restrict__ vdst,
    __bf16* __restrict__ hT, float* __restrict__ s_src, float* __restrict__ s_dst) {
    int lane = threadIdx.x & 63, w = threadIdx.x >> 6;
    int quad = lane >> 4, m = lane & 15;
    int Rbase = blockIdx.x * 64 + w * 16;
    int R = Rbase + m;
    const float* xr = x + (long)R * FIN;

    f32x4 acc[4] = {};
    float ps = 0.f, pd = 0.f;

#pragma unroll
    for (int k0 = 0; k0 < FIN; k0 += 32) {
        int kb = k0 + quad * 8;
        float4 x0 = *(const float4*)(xr + kb);
        float4 x1 = *(const float4*)(xr + kb + 4);
        float4 u0 = *(const float4*)(vsrc + kb);
        float4 u1 = *(const float4*)(vsrc + kb + 4);
        float4 t0 = *(const float4*)(vdst + kb);
        float4 t1 = *(const float4*)(vdst + kb + 4);
        ps += x0.x * u0.x + x0.y * u0.y + x0.z * u0.z + x0.w * u0.w +
              x1.x * u1.x + x1.y * u1.y + x1.z * u1.z + x1.w * u1.w;
        pd += x0.x * t0.x + x0.y * t0.y + x0.z * t0.z + x0.w * t0.w +
              x1.x * t1.x + x1.y * t1.y + x1.z * t1.z + x1.w * t1.w;
        bf16x8 bf = {(__bf16)x0.x, (__bf16)x0.y, (__bf16)x0.z, (__bf16)x0.w,
                     (__bf16)x1.x, (__bf16)x1.y, (__bf16)x1.z, (__bf16)x1.w};
#pragma unroll
        for (int ot = 0; ot < 4; ++ot) {
            bf16x8 af = *(const bf16x8*)(Wt + (ot * 16 + m) * FIN + kb);
            acc[ot] = __builtin_amdgcn_mfma_f32_16x16x32_bf16(af, bf, acc[ot], 0, 0, 0);
        }
    }
    ps += __shfl_xor(ps, 16);
    ps += __shfl_xor(ps, 32);
    pd += __shfl_xor(pd, 16);
    pd += __shfl_xor(pd, 32);
    if (quad == 0) {
        s_src[R] = ps;
        s_dst[R] = pd;
    }
    int b = R >> 11;
    int nb = Rbase & (NN - 1);
#pragma unroll
    for (int ot = 0; ot < 4; ++ot) {
#pragma unroll
        for (int r = 0; r < 4; ++r) {
            int o = ot * 16 + quad * 4 + r;
            hT[((long)b * FO + o) * NN + nb + m] = (__bf16)acc[ot][r];
        }
    }
}

// ---------------- K2: fused masked-softmax + PV, LDS-staged contiguous adj ----
// grid = 16 b * 32 itiles = 512 blocks; block = 4 waves; wave owns 16 i-rows.
// Per j-chunk of 512: 16 row-phases, each reading 2 KB CONTIGUOUS adj per wave
// (1 KB contiguous per instruction, every line fully consumed -> nt safe).
// P stored bf16 into per-wave LDS region in A-fragment layout; read back as
// ds_read_b128 for MFMA. Zero __syncthreads (all LDS traffic wave-local).
__global__ __launch_bounds__(256) void k2_attn(
    const int* __restrict__ adj, const float* __restrict__ s_src,
    const float* __restrict__ s_dst, const __bf16* __restrict__ hT,
    float* __restrict__ out) {
    __shared__ __bf16 pbuf[4][16 * CH];  // 4 waves x 16 KB = 64 KB
    int b = blockIdx.x >> 5;
    int i0 = (blockIdx.x & 31) << 6;
    int lane = threadIdx.x & 63, w = threadIdx.x >> 6;
    int quad = lane >> 4, m = lane & 15;
    int rowbase = i0 + w * 16;

    const float* sd = s_dst + b * NN;
    // wave-local max over s_dst[b][:] (j-independent stabilizer upper bound)
    float mx = -3.0e38f;
    for (int j = lane; j < NN; j += 64) mx = fmaxf(mx, sd[j]);
#pragma unroll
    for (int off = 32; off >= 1; off >>= 1) mx = fmaxf(mx, __shfl_xor(mx, off));

    const float* ssp = s_src + b * NN + rowbase;
    const int* adjb = adj + ((long)b * NN + rowbase) * NN;
    const __bf16* hTb = hT + (long)b * FO * NN;
    __bf16* pb = pbuf[w];

    f32x4 acc[4] = {};
    float lp = 0.f;

    for (int jc = 0; jc < NN; jc += CH) {
        // s_dst for this chunk: lane's two 4-j groups (reused across all 16 rows)
        float4 sv0 = *(const float4*)(sd + jc + 4 * lane);
        float4 sv1 = *(const float4*)(sd + jc + 256 + 4 * lane);
        // ---- staging phase: one row at a time, contiguous adj ----
#pragma unroll
        for (int r = 0; r < 16; ++r) {
            float sr = ssp[r];                  // wave-uniform (s_load)
            float M = fmaxf(sr + mx, 0.f);      // per-row stabilizer
            const int* ap = adjb + (long)r * NN + jc;
            i32x4 a0 = __builtin_nontemporal_load((const i32x4*)ap + lane);
            i32x4 a1 = __builtin_nontemporal_load((const i32x4*)(ap + 256) + lane);
            float p0 = (a0.x > 0) ? __expf(fmaxf(sr + sv0.x, 0.f) - M) : 0.f;
            float p1 = (a0.y > 0) ? __expf(fmaxf(sr + sv0.y, 0.f) - M) : 0.f;
            float p2 = (a0.z > 0) ? __expf(fmaxf(sr + sv0.z, 0.f) - M) : 0.f;
            float p3 = (a0.w > 0) ? __expf(fmaxf(sr + sv0.w, 0.f) - M) : 0.f;
            float p4 = (a1.x > 0) ? __expf(fmaxf(sr + sv1.x, 0.f) - M) : 0.f;
            float p5 = (a1.y > 0) ? __expf(fmaxf(sr + sv1.y, 0.f) - M) : 0.f;
            float p6 = (a1.z > 0) ? __expf(fmaxf(sr + sv1.z, 0.f) - M) : 0.f;
            float p7 = (a1.w > 0) ? __expf(fmaxf(sr + sv1.w, 0.f) - M) : 0.f;
            // A-frag layout: elem = (t>>5)*512 + r*32 + (t&31), t = j - jc
            bf16x4 k0v = {(__bf16)p0, (__bf16)p1, (__bf16)p2, (__bf16)p3};
            bf16x4 k1v = {(__bf16)p4, (__bf16)p5, (__bf16)p6, (__bf16)p7};
            int g0 = lane >> 3, u = (lane & 7) * 4;
            *(bf16x4*)(pb + g0 * 512 + r * 32 + u) = k0v;            // t0 = 4*lane
            *(bf16x4*)(pb + (8 + g0) * 512 + r * 32 + u) = k1v;      // t1 = 256+4*lane
        }
        // ---- MFMA phase: A-frags from LDS, B-frags (hT) from global/L2 ----
#pragma unroll
        for (int ks = 0; ks < CH / 32; ++ks) {
            bf16x8 af = *(const bf16x8*)(pb + (ks * 16 + m) * 32 + quad * 8);
#pragma unroll
            for (int e = 0; e < 8; ++e) lp += (float)af[e];  // row-m denom partial
            const __bf16* hb = hTb + jc + ks * 32 + quad * 8;
#pragma unroll
            for (int ot = 0; ot < 4; ++ot) {
                bf16x8 bf = *(const bf16x8*)(hb + (ot * 16 + m) * NN);
                acc[ot] = __builtin_amdgcn_mfma_f32_16x16x32_bf16(af, bf, acc[ot], 0, 0, 0);
            }
        }
    }

    // l_i: reduce across quads; lane m then holds l(row m)
    lp += __shfl_xor(lp, 16);
    lp += __shfl_xor(lp, 32);

    // epilogue: D layout col=lane&15 (o), row=quad*4+r (i-local)
    float* outp = out + ((long)b * NN + rowbase) * FO;
#pragma unroll
    for (int r = 0; r < 4; ++r) {
        int orow = quad * 4 + r;
        float lr = __shfl(lp, orow);
        float inv = 1.0f / lr;
#pragma unroll
        for (int ot = 0; ot < 4; ++ot) {
            outp[(long)orow * FO + ot * 16 + m] = acc[ot][r] * inv;
        }
    }
}

extern "C" void kernel_launch(void* const* d_in, const int* in_sizes, int n_in,
                              void* d_out, int out_size, void* d_ws, size_t ws_size,
                              hipStream_t stream) {
    const float* x      = (const float*)d_in[0];
    const int*   adj    = (const int*)d_in[1];
    const float* weight = (const float*)d_in[2];
    const float* w2     = (const float*)d_in[3];
    float* out = (float*)d_out;

    char* ws = (char*)d_ws;
    __bf16* hT   = (__bf16*)ws;                               // 4 MB
    float* s_src = (float*)(ws + 4194304);                    // 128 KB
    float* s_dst = (float*)(ws + 4194304 + 131072);           // 128 KB
    float* vsrc  = (float*)(ws + 4194304 + 262144);           // 1 KB
    float* vdst  = (float*)(ws + 4194304 + 262144 + 1024);    // 1 KB
    __bf16* Wt   = (__bf16*)(ws + 4194304 + 262144 + 2048);   // 32 KB

    k0_prep<<<1, 256, 0, stream>>>(weight, w2, Wt, vsrc, vdst);
    k1_gemm<<<512, 256, 0, stream>>>(x, Wt, vsrc, vdst, hT, s_src, s_dst);
    k2_attn<<<512, 256, 0, stream>>>(adj, s_src, s_dst, hT, out);
}

// Round 3
// 476.948 us; speedup vs baseline: 1.0030x; 1.0030x over previous
//
#include <hip/hip_runtime.h>
#include <hip/hip_bf16.h>

#define BB 16
#define NN 2048
#define FIN 256
#define FO 64
#define PADW 264   // LDS leading-dim pad for Wt (breaks 512B-stride bank aliasing)
#define CH 256     // k2 j-chunk per staging round (32 KB LDS -> 4 blocks/CU)

typedef __bf16 bf16x8 __attribute__((ext_vector_type(8)));
typedef __bf16 bf16x4 __attribute__((ext_vector_type(4)));
typedef float  f32x4  __attribute__((ext_vector_type(4)));
typedef int    i32x4  __attribute__((ext_vector_type(4)));

// ---------------- K1: h GEMM (MFMA bf16) + exact fp32 s_src/s_dst ------------
// k0 folded in: each block redundantly stages W->LDS (bf16, transposed, padded)
// and computes vsrc/vdst (fp32 logit vectors) — ~1 us, removes the serialized
// single-block prep kernel entirely.
__global__ __launch_bounds__(256) void k1_gemm(
    const float* __restrict__ x, const float* __restrict__ weight,
    const float* __restrict__ w2,
    __bf16* __restrict__ hT, float* __restrict__ s_src, float* __restrict__ s_dst) {
    __shared__ __bf16 WtL[FO * PADW];          // 33 KB
    __shared__ float vsL[FIN], vdL[FIN];       // 2 KB
    int t = threadIdx.x;  // 256 threads; thread t owns W row k=t (64 floats)
    {
        const float4* wr = (const float4*)(weight + t * FO);
        float a = 0.f, d = 0.f;
#pragma unroll
        for (int c = 0; c < 16; ++c) {
            float4 v = wr[c];
            int o = c * 4;
            WtL[(o + 0) * PADW + t] = (__bf16)v.x;
            WtL[(o + 1) * PADW + t] = (__bf16)v.y;
            WtL[(o + 2) * PADW + t] = (__bf16)v.z;
            WtL[(o + 3) * PADW + t] = (__bf16)v.w;
            a += v.x * w2[o] + v.y * w2[o + 1] + v.z * w2[o + 2] + v.w * w2[o + 3];
            d += v.x * w2[FO + o] + v.y * w2[FO + o + 1] +
                 v.z * w2[FO + o + 2] + v.w * w2[FO + o + 3];
        }
        vsL[t] = a;
        vdL[t] = d;
    }
    __syncthreads();

    int lane = threadIdx.x & 63, w = threadIdx.x >> 6;
    int quad = lane >> 4, m = lane & 15;
    int Rbase = blockIdx.x * 64 + w * 16;
    int R = Rbase + m;
    const float* xr = x + (long)R * FIN;

    f32x4 acc[4] = {};
    float ps = 0.f, pd = 0.f;

#pragma unroll
    for (int k0 = 0; k0 < FIN; k0 += 32) {
        int kb = k0 + quad * 8;
        float4 x0 = *(const float4*)(xr + kb);
        float4 x1 = *(const float4*)(xr + kb + 4);
        float4 u0 = *(const float4*)(vsL + kb);
        float4 u1 = *(const float4*)(vsL + kb + 4);
        float4 t0 = *(const float4*)(vdL + kb);
        float4 t1 = *(const float4*)(vdL + kb + 4);
        ps += x0.x * u0.x + x0.y * u0.y + x0.z * u0.z + x0.w * u0.w +
              x1.x * u1.x + x1.y * u1.y + x1.z * u1.z + x1.w * u1.w;
        pd += x0.x * t0.x + x0.y * t0.y + x0.z * t0.z + x0.w * t0.w +
              x1.x * t1.x + x1.y * t1.y + x1.z * t1.z + x1.w * t1.w;
        bf16x8 bf = {(__bf16)x0.x, (__bf16)x0.y, (__bf16)x0.z, (__bf16)x0.w,
                     (__bf16)x1.x, (__bf16)x1.y, (__bf16)x1.z, (__bf16)x1.w};
#pragma unroll
        for (int ot = 0; ot < 4; ++ot) {
            bf16x8 af = *(const bf16x8*)(WtL + (ot * 16 + m) * PADW + kb);
            acc[ot] = __builtin_amdgcn_mfma_f32_16x16x32_bf16(af, bf, acc[ot], 0, 0, 0);
        }
    }
    ps += __shfl_xor(ps, 16);
    ps += __shfl_xor(ps, 32);
    pd += __shfl_xor(pd, 16);
    pd += __shfl_xor(pd, 32);
    if (quad == 0) {
        s_src[R] = ps;
        s_dst[R] = pd;
    }
    int b = R >> 11;
    int nb = Rbase & (NN - 1);
#pragma unroll
    for (int ot = 0; ot < 4; ++ot) {
#pragma unroll
        for (int r = 0; r < 4; ++r) {
            int o = ot * 16 + quad * 4 + r;
            hT[((long)b * FO + o) * NN + nb + m] = (__bf16)acc[ot][r];
        }
    }
}

// ---------------- K2: fused masked-softmax + PV, LDS-staged contiguous adj ----
// grid = 16 b * 32 itiles; block = 4 waves; wave owns 16 i-rows. Zero barriers.
// Per 256-j chunk: 16 row-phases each read 1 KB contiguous adj per wave (nt),
// P staged bf16 into per-wave LDS in A-frag layout; denominator accumulated by
// a 5th MFMA against a ones B-fragment (lands in C-layout, no epilogue shfl).
__global__ __launch_bounds__(256) void k2_attn(
    const int* __restrict__ adj, const float* __restrict__ s_src,
    const float* __restrict__ s_dst, const __bf16* __restrict__ hT,
    float* __restrict__ out) {
    __shared__ __bf16 pbuf[4][16 * CH];  // 4 waves x 8 KB = 32 KB
    int b = blockIdx.x >> 5;
    int i0 = (blockIdx.x & 31) << 6;
    int lane = threadIdx.x & 63, w = threadIdx.x >> 6;
    int quad = lane >> 4, m = lane & 15;
    int rowbase = i0 + w * 16;

    const float* sd = s_dst + b * NN;
    float mx = -3.0e38f;
    for (int j = lane; j < NN; j += 64) mx = fmaxf(mx, sd[j]);
#pragma unroll
    for (int off = 32; off >= 1; off >>= 1) mx = fmaxf(mx, __shfl_xor(mx, off));

    const float* ssp = s_src + b * NN + rowbase;
    const int* adjb = adj + ((long)b * NN + rowbase) * NN;
    const __bf16* hTb = hT + (long)b * FO * NN;
    __bf16* pb = pbuf[w];

    f32x4 acc[4] = {};
    f32x4 accL = {};
    const bf16x8 ones = {(__bf16)1.f, (__bf16)1.f, (__bf16)1.f, (__bf16)1.f,
                         (__bf16)1.f, (__bf16)1.f, (__bf16)1.f, (__bf16)1.f};
    int g0 = lane >> 3, u = (lane & 7) * 4;

    for (int jc = 0; jc < NN; jc += CH) {
        float4 sv = *(const float4*)(sd + jc + 4 * lane);
        // ---- staging: one row at a time, contiguous 1 KB adj per wave ----
#pragma unroll
        for (int r = 0; r < 16; ++r) {
            float sr = ssp[r];               // wave-uniform
            float M = fmaxf(sr + mx, 0.f);   // per-row stabilizer (j-indep bound)
            i32x4 a0 = __builtin_nontemporal_load(
                (const i32x4*)(adjb + (long)r * NN + jc) + lane);
            float p0 = (a0.x > 0) ? __expf(fmaxf(sr + sv.x, 0.f) - M) : 0.f;
            float p1 = (a0.y > 0) ? __expf(fmaxf(sr + sv.y, 0.f) - M) : 0.f;
            float p2 = (a0.z > 0) ? __expf(fmaxf(sr + sv.z, 0.f) - M) : 0.f;
            float p3 = (a0.w > 0) ? __expf(fmaxf(sr + sv.w, 0.f) - M) : 0.f;
            bf16x4 kv = {(__bf16)p0, (__bf16)p1, (__bf16)p2, (__bf16)p3};
            // A-frag layout: elem = (t>>5)*512 + r*32 + (t&31), t = 4*lane
            *(bf16x4*)(pb + g0 * 512 + r * 32 + u) = kv;
        }
        // ---- MFMA phase: A-frags from LDS, B-frags (hT) from L2 ----
#pragma unroll
        for (int ks = 0; ks < CH / 32; ++ks) {
            bf16x8 af = *(const bf16x8*)(pb + ks * 512 + m * 32 + quad * 8);
            accL = __builtin_amdgcn_mfma_f32_16x16x32_bf16(af, ones, accL, 0, 0, 0);
            const __bf16* hb = hTb + jc + ks * 32 + quad * 8;
#pragma unroll
            for (int ot = 0; ot < 4; ++ot) {
                bf16x8 bf = *(const bf16x8*)(hb + (ot * 16 + m) * NN);
                acc[ot] = __builtin_amdgcn_mfma_f32_16x16x32_bf16(af, bf, acc[ot], 0, 0, 0);
            }
        }
    }

    // epilogue: D layout col=lane&15 (o), row=quad*4+r (i-local); accL[r] is
    // the row denominator (P . ones), identical mapping — no shuffles needed.
    float* outp = out + ((long)b * NN + rowbase) * FO;
#pragma unroll
    for (int r = 0; r < 4; ++r) {
        int orow = quad * 4 + r;
        float inv = 1.0f / accL[r];
#pragma unroll
        for (int ot = 0; ot < 4; ++ot) {
            outp[(long)orow * FO + ot * 16 + m] = acc[ot][r] * inv;
        }
    }
}

extern "C" void kernel_launch(void* const* d_in, const int* in_sizes, int n_in,
                              void* d_out, int out_size, void* d_ws, size_t ws_size,
                              hipStream_t stream) {
    const float* x      = (const float*)d_in[0];
    const int*   adj    = (const int*)d_in[1];
    const float* weight = (const float*)d_in[2];
    const float* w2     = (const float*)d_in[3];
    float* out = (float*)d_out;

    char* ws = (char*)d_ws;
    __bf16* hT   = (__bf16*)ws;                     // 16*64*2048*2 = 4 MB
    float* s_src = (float*)(ws + 4194304);          // 128 KB
    float* s_dst = (float*)(ws + 4194304 + 131072); // 128 KB

    k1_gemm<<<512, 256, 0, stream>>>(x, weight, w2, hT, s_src, s_dst);
    k2_attn<<<512, 256, 0, stream>>>(adj, s_src, s_dst, hT, out);
}

// Round 4
// 428.491 us; speedup vs baseline: 1.1165x; 1.1131x over previous
//
#include <hip/hip_runtime.h>
#include <hip/hip_bf16.h>

#define BB 16
#define NN 2048
#define FIN 256
#define FO 64

typedef __bf16 bf16x8 __attribute__((ext_vector_type(8)));
typedef float  f32x4  __attribute__((ext_vector_type(4)));
typedef int    i32x4  __attribute__((ext_vector_type(4)));
typedef unsigned int uint;

// ---------------- K1: h GEMM (MFMA bf16) + exact fp32 s_src/s_dst ------------
__global__ __launch_bounds__(256) void k1_gemm(
    const float* __restrict__ x, const float* __restrict__ weight,
    const float* __restrict__ w2,
    __bf16* __restrict__ hT, float* __restrict__ s_src, float* __restrict__ s_dst) {
    __shared__ __bf16 WtL[FO * 264];
    __shared__ float vsL[FIN], vdL[FIN];
    int t = threadIdx.x;
    {
        const float4* wr = (const float4*)(weight + t * FO);
        float a = 0.f, d = 0.f;
#pragma unroll
        for (int c = 0; c < 16; ++c) {
            float4 v = wr[c];
            int o = c * 4;
            WtL[(o + 0) * 264 + t] = (__bf16)v.x;
            WtL[(o + 1) * 264 + t] = (__bf16)v.y;
            WtL[(o + 2) * 264 + t] = (__bf16)v.z;
            WtL[(o + 3) * 264 + t] = (__bf16)v.w;
            a += v.x * w2[o] + v.y * w2[o + 1] + v.z * w2[o + 2] + v.w * w2[o + 3];
            d += v.x * w2[FO + o] + v.y * w2[FO + o + 1] +
                 v.z * w2[FO + o + 2] + v.w * w2[FO + o + 3];
        }
        vsL[t] = a;
        vdL[t] = d;
    }
    __syncthreads();

    int lane = threadIdx.x & 63, w = threadIdx.x >> 6;
    int quad = lane >> 4, m = lane & 15;
    int Rbase = blockIdx.x * 64 + w * 16;
    int R = Rbase + m;
    const float* xr = x + (long)R * FIN;

    f32x4 acc[4] = {};
    float ps = 0.f, pd = 0.f;

#pragma unroll
    for (int k0 = 0; k0 < FIN; k0 += 32) {
        int kb = k0 + quad * 8;
        float4 x0 = *(const float4*)(xr + kb);
        float4 x1 = *(const float4*)(xr + kb + 4);
        float4 u0 = *(const float4*)(vsL + kb);
        float4 u1 = *(const float4*)(vsL + kb + 4);
        float4 t0 = *(const float4*)(vdL + kb);
        float4 t1 = *(const float4*)(vdL + kb + 4);
        ps += x0.x * u0.x + x0.y * u0.y + x0.z * u0.z + x0.w * u0.w +
              x1.x * u1.x + x1.y * u1.y + x1.z * u1.z + x1.w * u1.w;
        pd += x0.x * t0.x + x0.y * t0.y + x0.z * t0.z + x0.w * t0.w +
              x1.x * t1.x + x1.y * t1.y + x1.z * t1.z + x1.w * t1.w;
        bf16x8 bf = {(__bf16)x0.x, (__bf16)x0.y, (__bf16)x0.z, (__bf16)x0.w,
                     (__bf16)x1.x, (__bf16)x1.y, (__bf16)x1.z, (__bf16)x1.w};
#pragma unroll
        for (int ot = 0; ot < 4; ++ot) {
            bf16x8 af = *(const bf16x8*)(WtL + (ot * 16 + m) * 264 + kb);
            acc[ot] = __builtin_amdgcn_mfma_f32_16x16x32_bf16(af, bf, acc[ot], 0, 0, 0);
        }
    }
    ps += __shfl_xor(ps, 16);
    ps += __shfl_xor(ps, 32);
    pd += __shfl_xor(pd, 16);
    pd += __shfl_xor(pd, 32);
    if (quad == 0) {
        s_src[R] = ps;
        s_dst[R] = pd;
    }
    int b = R >> 11;
    int nb = Rbase & (NN - 1);
#pragma unroll
    for (int ot = 0; ot < 4; ++ot) {
#pragma unroll
        for (int r = 0; r < 4; ++r) {
            int o = ot * 16 + quad * 4 + r;
            hT[((long)b * FO + o) * NN + nb + m] = (__bf16)acc[ot][r];
        }
    }
}

// ---------------- K_PACK: adj int32 -> 1-bit mask (268 MB -> 8.4 MB) ---------
// Pure stream: thread t packs adj[t*8 .. t*8+8) into one byte. 32 B/lane reads
// (2x dwordx4, nontemporal), 64 consecutive byte-stores per wave.
__global__ __launch_bounds__(256) void k_pack(const int* __restrict__ adj,
                                              unsigned char* __restrict__ mask) {
    size_t t = (size_t)blockIdx.x * 256 + threadIdx.x;
    const i32x4* ap = (const i32x4*)(adj + t * 8);
    i32x4 a0 = __builtin_nontemporal_load(ap);
    i32x4 a1 = __builtin_nontemporal_load(ap + 1);
    unsigned b = (unsigned)(a0.x > 0) | ((unsigned)(a0.y > 0) << 1) |
                 ((unsigned)(a0.z > 0) << 2) | ((unsigned)(a0.w > 0) << 3) |
                 ((unsigned)(a1.x > 0) << 4) | ((unsigned)(a1.y > 0) << 5) |
                 ((unsigned)(a1.z > 0) << 6) | ((unsigned)(a1.w > 0) << 7);
    mask[t] = (unsigned char)b;
}

// ---------------- K2: fused masked-softmax + PV from bitmask -----------------
// grid = 16 b * 32 itiles = 512 blocks; block = 4 waves; wave owns 16 i-rows.
// Lane (m,q) owns row m's mask dwords q*16..q*16+15 in 16 VGPRs; per k-step
// one __shfl routes dword ks to all quads. P built directly in A-frag regs
// (no LDS staging, no in-loop barriers). s_dst in LDS, broadcast reads.
// Denominator via 5th MFMA against ones (C-layout, no epilogue shuffles).
__global__ __launch_bounds__(256) void k2_attn(
    const unsigned char* __restrict__ mask, const float* __restrict__ s_src,
    const float* __restrict__ s_dst, const __bf16* __restrict__ hT,
    float* __restrict__ out) {
    __shared__ float sdL[NN];
    int b = blockIdx.x >> 5;
    int i0 = (blockIdx.x & 31) << 6;
    int lane = threadIdx.x & 63;
    int w = threadIdx.x >> 6;
    int quad = lane >> 4, m = lane & 15;
    int rowbase = i0 + w * 16;

    // stage s_dst[b][:] into LDS (block-cooperative, one barrier)
    {
        const float4* sp = (const float4*)(s_dst + b * NN);
        float4* dp = (float4*)sdL;
        for (int t = threadIdx.x; t < NN / 4; t += 256) dp[t] = sp[t];
    }
    __syncthreads();

    // wave max over s_dst (j-independent stabilizer upper bound)
    float mx = -3.0e38f;
    for (int j = lane; j < NN; j += 64) mx = fmaxf(mx, sdL[j]);
#pragma unroll
    for (int off = 32; off >= 1; off >>= 1) mx = fmaxf(mx, __shfl_xor(mx, off));

    float ssr = s_src[b * NN + rowbase + m];  // this lane's row logit (exact fp32)
    float M = fmaxf(ssr + mx, 0.f);

    // this lane's mask slice: row (rowbase+m), dwords quad*16 .. quad*16+15
    const uint4* mp = (const uint4*)(mask + ((size_t)(b * NN + rowbase + m)) * 256 +
                                     quad * 64);
    uint4 mw0 = mp[0], mw1 = mp[1], mw2 = mp[2], mw3 = mp[3];
    uint dw[16] = {mw0.x, mw0.y, mw0.z, mw0.w, mw1.x, mw1.y, mw1.z, mw1.w,
                   mw2.x, mw2.y, mw2.z, mw2.w, mw3.x, mw3.y, mw3.z, mw3.w};

    const __bf16* hTb = hT + (long)b * FO * NN;
    f32x4 acc[4] = {};
    f32x4 accL = {};
    const bf16x8 ones = {(__bf16)1.f, (__bf16)1.f, (__bf16)1.f, (__bf16)1.f,
                         (__bf16)1.f, (__bf16)1.f, (__bf16)1.f, (__bf16)1.f};
    int q8 = quad * 8;

    for (int qo = 0; qo < 4; ++qo) {
        int src = (qo << 4) | m;  // owner lane of dword ks for my row m
#pragma unroll
        for (int u = 0; u < 16; ++u) {
            int ks = (qo << 4) | u;
            uint mv = (uint)__shfl((int)dw[u], src);
            const float* sp = sdL + ks * 32 + q8;
            float4 s0 = *(const float4*)sp;
            float4 s1 = *(const float4*)(sp + 4);
            float p0 = ((mv >> (q8 + 0)) & 1) ? __expf(fmaxf(ssr + s0.x, 0.f) - M) : 0.f;
            float p1 = ((mv >> (q8 + 1)) & 1) ? __expf(fmaxf(ssr + s0.y, 0.f) - M) : 0.f;
            float p2 = ((mv >> (q8 + 2)) & 1) ? __expf(fmaxf(ssr + s0.z, 0.f) - M) : 0.f;
            float p3 = ((mv >> (q8 + 3)) & 1) ? __expf(fmaxf(ssr + s0.w, 0.f) - M) : 0.f;
            float p4 = ((mv >> (q8 + 4)) & 1) ? __expf(fmaxf(ssr + s1.x, 0.f) - M) : 0.f;
            float p5 = ((mv >> (q8 + 5)) & 1) ? __expf(fmaxf(ssr + s1.y, 0.f) - M) : 0.f;
            float p6 = ((mv >> (q8 + 6)) & 1) ? __expf(fmaxf(ssr + s1.z, 0.f) - M) : 0.f;
            float p7 = ((mv >> (q8 + 7)) & 1) ? __expf(fmaxf(ssr + s1.w, 0.f) - M) : 0.f;
            bf16x8 af = {(__bf16)p0, (__bf16)p1, (__bf16)p2, (__bf16)p3,
                         (__bf16)p4, (__bf16)p5, (__bf16)p6, (__bf16)p7};
            accL = __builtin_amdgcn_mfma_f32_16x16x32_bf16(af, ones, accL, 0, 0, 0);
            const __bf16* hb = hTb + ks * 32 + q8;
#pragma unroll
            for (int ot = 0; ot < 4; ++ot) {
                bf16x8 bf = *(const bf16x8*)(hb + (ot * 16 + m) * NN);
                acc[ot] = __builtin_amdgcn_mfma_f32_16x16x32_bf16(af, bf, acc[ot], 0, 0, 0);
            }
        }
    }

    // epilogue: D layout col=lane&15 (o), row=quad*4+r (i-local); accL[r] = denom
    float* outp = out + ((long)b * NN + rowbase) * FO;
#pragma unroll
    for (int r = 0; r < 4; ++r) {
        int orow = quad * 4 + r;
        float inv = 1.0f / accL[r];
#pragma unroll
        for (int ot = 0; ot < 4; ++ot) {
            outp[(long)orow * FO + ot * 16 + m] = acc[ot][r] * inv;
        }
    }
}

extern "C" void kernel_launch(void* const* d_in, const int* in_sizes, int n_in,
                              void* d_out, int out_size, void* d_ws, size_t ws_size,
                              hipStream_t stream) {
    const float* x      = (const float*)d_in[0];
    const int*   adj    = (const int*)d_in[1];
    const float* weight = (const float*)d_in[2];
    const float* w2     = (const float*)d_in[3];
    float* out = (float*)d_out;

    char* ws = (char*)d_ws;
    __bf16* hT   = (__bf16*)ws;                              // 4 MB
    float* s_src = (float*)(ws + 4194304);                   // 128 KB
    float* s_dst = (float*)(ws + 4194304 + 131072);          // 128 KB
    unsigned char* mask = (unsigned char*)(ws + 4194304 + 262144);  // 8 MB

    k_pack<<<32768, 256, 0, stream>>>(adj, mask);
    k1_gemm<<<512, 256, 0, stream>>>(x, weight, w2, hT, s_src, s_dst);
    k2_attn<<<512, 256, 0, stream>>>(mask, s_src, s_dst, hT, out);
}